// Round 8
// baseline (271.735 us; speedup 1.0000x reference)
//
#include <hip/hip_runtime.h>
#include <cstdint>
#include <cstddef>

// Attention: B=4, S=2048, H=1024 (single "head", d=1024). fp32 I/O buffers.
// Pipeline: cvt x,W* to bf16 (1 kernel) ; fused QKV GEMM (N=3072 -> Q,K,Vt) ;
//           Sc = Q·Kᵀ/32 (fp16) ; P = softmax(Sc) (bf16) ; out = P·Vtᵀ (fp32).
// R7 post-mortem: QKV 73µs @705TF, MfmaUtil 29; LDS pipe ~65% of wall
//   (96KB/block-iter: 32 DMA-write + 64 fragment-read; reuse only 4x at
//   64x64 wave tile). Scores/PV below top-5 but ~60µs each.
// R8: wave tile 64x128 (acc 4x8, LDS reads/MAC -23%, 2x MFMA per B-fragment),
//   block 128x256, BK=32 dbuf (48KB) for QKV+scores. PV keeps 128x128/BK=64
//   (grid too small for 256-wide tiles). cvts fused into one kernel.
// ws layout (102 MB): [0,16M) xb ; [16,22M) Wqkv bf16 (Wq|Wk|Wv) ;
//   [22,38M) Q ; [38,54M) Kp ; [54,70M) Vt ; [70,102M) Sc fp16 ;
//   P overlays [22,54M) (Q|Kp dead after scores GEMM).

typedef __bf16 bf16;
typedef _Float16 f16;
typedef __bf16 bf16x8 __attribute__((ext_vector_type(8)));
typedef __bf16 bf16x4 __attribute__((ext_vector_type(4)));
typedef float f32x4 __attribute__((ext_vector_type(4)));

// Fused fp32->bf16 convert: x (XQ quads) -> xb, then Wq|Wk|Wv (WQ quads each)
// -> contiguous Wqkv. One dispatch.
#define XQ (8388608 / 4)
#define WQ (1048576 / 4)
__global__ __launch_bounds__(256)
void cvt_all(const float* __restrict__ x, const float* __restrict__ Wq,
             const float* __restrict__ Wk, const float* __restrict__ Wv,
             bf16* __restrict__ xb, bf16* __restrict__ Wqkv)
{
    const int i = blockIdx.x * 256 + threadIdx.x;
    const float* src;
    bf16* dst;
    if (i < XQ) {
        src = x + 4 * (size_t)i;
        dst = xb + 4 * (size_t)i;
    } else {
        const int j = i - XQ;                 // 0 .. 3*WQ-1
        const int w = j / WQ;                 // 0..2
        const int off = j - w * WQ;
        const float* ws_ = (w == 0) ? Wq : (w == 1) ? Wk : Wv;
        src = ws_ + 4 * (size_t)off;
        dst = Wqkv + 4 * (size_t)j;
    }
    f32x4 v = *(const f32x4*)src;
    bf16x4 o;
#pragma unroll
    for (int r = 0; r < 4; ++r) o[r] = (bf16)v[r];
    *(bf16x4*)dst = o;
}

// Bank swizzle (both measured conflict-free: R5 table for BK=32 variant,
// R6 table for BK=64 variant).
template <int BKT>
__device__ __forceinline__ int swz(int cp, int row)
{
    return (BKT == 64) ? (cp ^ (row & 7)) : (cp ^ ((row >> 1) & 3));
}

// Stage one ROWS x BKT bf16 tile global -> LDS via global_load_lds w=16.
// Lane at linear chunk p stores LDS slot p (DMA: wave-uniform base + lane*16,
// m104) and fetches global chunk swz(p%C, row) of row p/C.
template <int ROWS, int BKT>
__device__ __forceinline__ void stage_tile(const bf16* __restrict__ g, int ld,
                                           bf16* lds_generic, int tid)
{
    constexpr int C = BKT / 8;
    constexpr int ISSUES = ROWS * C / 256;
    auto lds3 = (__attribute__((address_space(3))) char*)lds_generic;
    const int wave = tid >> 6;
#pragma unroll
    for (int issue = 0; issue < ISSUES; ++issue) {
        const int p   = issue * 256 + tid;
        const int row = p / C;
        const int cp  = p % C;
        const int c   = swz<BKT>(cp, row);
        const bf16* gp = g + (size_t)row * ld + c * 8;
        const unsigned wave_base = (unsigned)(issue * 4096 + wave * 1024);
        __builtin_amdgcn_global_load_lds(
            (const __attribute__((address_space(1))) void*)gp,
            (__attribute__((address_space(3))) void*)(lds3 + wave_base),
            16, 0, 0);
    }
}

template <int BKT>
__device__ __forceinline__ bf16x8 read_frag(const bf16* lds, int row, int chunk)
{
    const int cp = swz<BKT>(chunk, row);
    return *(const bf16x8*)(lds + row * BKT + cp * 8);
}

// OUTMODE: 2 = f16 out, scaled by alpha (scores)
//          3 = f32 out (final O -> d_out)
//          4 = fused QKV: col3>>10 selects {Q,K,Vt}; bias0/1/2 = bq/bk/bv.
// WN = wave-tile N-width in 16-col units (4 or 8). Block = 128 x (WN*32).
template <int OUTMODE, int WN, int BKT>
__global__ __launch_bounds__(256, 2)
void gemm_bt(const bf16* __restrict__ A, const bf16* __restrict__ Bm,
             const float* __restrict__ bias0, const float* __restrict__ bias1,
             const float* __restrict__ bias2, void* __restrict__ C,
             int K, int N, float alpha, long zA, long zB, long zC)
{
    constexpr int BM = 128;
    constexpr int BN = WN * 32;
    __shared__ alignas(16) bf16 As[2][BM * BKT];
    __shared__ alignas(16) bf16 Bs[2][BN * BKT];

    const int tid  = threadIdx.x;
    const int lane = tid & 63;
    const int wid  = tid >> 6;
    const int wr   = (wid >> 1) * 64;        // wave row offset in tile
    const int wc   = (wid & 1) * (WN * 16);  // wave col offset in tile
    const int quad = lane >> 4;
    const int l16  = lane & 15;

    const int m0 = blockIdx.y * BM;
    const int n0 = blockIdx.x * BN;
    const int z  = blockIdx.z;

    const bf16* Ab = A + (size_t)z * zA + (size_t)m0 * K;
    const bf16* Bb = Bm + (size_t)z * zB + (size_t)n0 * K;

    f32x4 acc[4][WN] = {};

    // Prologue: stage tile 0 into buffer 0.
    stage_tile<BM, BKT>(Ab, K, As[0], tid);
    stage_tile<BN, BKT>(Bb, K, Bs[0], tid);

    const int niter = K / BKT;
    for (int it = 0; it < niter; ++it) {
        const int cur = it & 1;
        __syncthreads();   // drains vmcnt: buf[cur] staged; prior compute done
        if (it + 1 < niter) {
            stage_tile<BM, BKT>(Ab + (it + 1) * BKT, K, As[cur ^ 1], tid);
            stage_tile<BN, BKT>(Bb + (it + 1) * BKT, K, Bs[cur ^ 1], tid);
        }
#pragma unroll
        for (int h = 0; h < BKT / 32; ++h) {
            bf16x8 af[4], bfr[WN];
#pragma unroll
            for (int i = 0; i < 4; ++i)
                af[i]  = read_frag<BKT>(As[cur], wr + i * 16 + l16, h * 4 + quad);
#pragma unroll
            for (int j = 0; j < WN; ++j)
                bfr[j] = read_frag<BKT>(Bs[cur], wc + j * 16 + l16, h * 4 + quad);

#pragma unroll
            for (int i = 0; i < 4; ++i)
#pragma unroll
                for (int j = 0; j < WN; ++j)
                    acc[i][j] = __builtin_amdgcn_mfma_f32_16x16x32_bf16(
                        af[i], bfr[j], acc[i][j], 0, 0, 0);
        }
    }

    // Epilogue. C/D layout (verified m89): col = lane&15, row = quad*4 + reg.
#pragma unroll
    for (int j = 0; j < WN; ++j) {
        const int col3 = n0 + wc + j * 16 + l16;
#pragma unroll
        for (int i = 0; i < 4; ++i) {
            const int rbase = m0 + wr + i * 16 + quad * 4;
            if (OUTMODE == 2) {
                f16* Cf = (f16*)C + (size_t)z * zC;
#pragma unroll
                for (int r = 0; r < 4; ++r)
                    Cf[(size_t)(rbase + r) * N + col3] = (f16)(acc[i][j][r] * alpha);
            } else if (OUTMODE == 3) {
                float* Cf = (float*)C + (size_t)z * zC;
#pragma unroll
                for (int r = 0; r < 4; ++r)
                    Cf[(size_t)(rbase + r) * N + col3] = acc[i][j][r];
            } else { // OUTMODE == 4
                const int mat = col3 >> 10;           // 0=Q 1=K 2=V (uniform/blk)
                const int col = col3 & 1023;
                const float* bp = (mat == 0) ? bias0 : (mat == 1) ? bias1 : bias2;
                const float bj = bp[col];
                if (mat < 2) {
                    bf16* Cb = (bf16*)C + (size_t)mat * (8u << 20);
#pragma unroll
                    for (int r = 0; r < 4; ++r)
                        Cb[(size_t)(rbase + r) * 1024 + col] =
                            (bf16)(acc[i][j][r] + bj);
                } else {
                    // Vt[b][col][s] = V[b*2048+s][col]; quad rows are 4
                    // consecutive s -> one 8B same-type vector store.
                    bf16* Cb = (bf16*)C + (size_t)(16u << 20);
                    const int b = rbase >> 11;
                    const int s = rbase & 2047;
                    bf16x4 tmp;
#pragma unroll
                    for (int r = 0; r < 4; ++r) tmp[r] = (bf16)(acc[i][j][r] + bj);
                    *(bf16x4*)(Cb + (((size_t)((b << 10) + col)) << 11) + s) = tmp;
                }
            }
        }
    }
}

__device__ __forceinline__ float wred_max(float v)
{
#pragma unroll
    for (int o = 32; o > 0; o >>= 1) v = fmaxf(v, __shfl_xor(v, o, 64));
    return v;
}
__device__ __forceinline__ float wred_sum(float v)
{
#pragma unroll
    for (int o = 32; o > 0; o >>= 1) v += __shfl_xor(v, o, 64);
    return v;
}

__global__ __launch_bounds__(256)
void softmax_rows(const f16* __restrict__ Sc, bf16* __restrict__ P)
{
    constexpr int NC = 2048;
    const size_t row = blockIdx.x;
    const f16* src = Sc + row * NC;
    bf16* dst = P + row * NC;
    const int tid = threadIdx.x;

    float v[8];
    float m = -3.4e38f;
#pragma unroll
    for (int i = 0; i < 8; ++i) {
        v[i] = (float)src[tid + 256 * i];
        m = fmaxf(m, v[i]);
    }
    m = wred_max(m);

    __shared__ float redm[4], reds[4];
    if ((tid & 63) == 0) redm[tid >> 6] = m;
    __syncthreads();
    m = fmaxf(fmaxf(redm[0], redm[1]), fmaxf(redm[2], redm[3]));

    float s = 0.f;
#pragma unroll
    for (int i = 0; i < 8; ++i) { v[i] = __expf(v[i] - m); s += v[i]; }
    s = wred_sum(s);
    if ((tid & 63) == 0) reds[tid >> 6] = s;
    __syncthreads();
    s = reds[0] + reds[1] + reds[2] + reds[3];

    const float inv = 1.f / s;
#pragma unroll
    for (int i = 0; i < 8; ++i) dst[tid + 256 * i] = (bf16)(v[i] * inv);
}

extern "C" void kernel_launch(void* const* d_in, const int* in_sizes, int n_in,
                              void* d_out, int out_size, void* d_ws, size_t ws_size,
                              hipStream_t stream)
{
    constexpr int B = 4, S = 2048, H = 1024;
    const float* x  = (const float*)d_in[0];
    const float* Wq = (const float*)d_in[1];
    const float* bq = (const float*)d_in[2];
    const float* Wk = (const float*)d_in[3];
    const float* bk = (const float*)d_in[4];
    const float* Wv = (const float*)d_in[5];
    const float* bv = (const float*)d_in[6];
    float* out = (float*)d_out;

    char* ws = (char*)d_ws;
    bf16* xb   = (bf16*)ws;                         // 16 MB
    bf16* Wqkv = (bf16*)(ws + (size_t)(16 << 20));  //  6 MB (Wq|Wk|Wv bf16)
    bf16* Q    = (bf16*)(ws + (size_t)(22 << 20));  // 16 MB
    bf16* Kp   = (bf16*)(ws + (size_t)(38 << 20));  // 16 MB (Q + 8M elems)
    bf16* Vt   = (bf16*)(ws + (size_t)(54 << 20));  // 16 MB (Q + 16M elems)
    f16*  Sc   = (f16*) (ws + (size_t)(70 << 20));  // 32 MB (fp16 scores)
    bf16* P    = (bf16*)(ws + (size_t)(22 << 20));  // 32 MB, overlays Q|Kp

    dim3 blk(256, 1, 1);

    // fp32 -> bf16 conversions, one dispatch (x -> xb, Wq|Wk|Wv -> Wqkv)
    cvt_all<<<dim3((XQ + 3 * WQ) / 256), blk, 0, stream>>>(
        x, Wq, Wk, Wv, xb, Wqkv);

    // Fused QKV projection: M = 8192, N = 3072, K = 1024 -> Q, Kp, Vt
    gemm_bt<4, 8, 32><<<dim3(3 * H / 256, (B * S) / 128, 1), blk, 0, stream>>>(
        xb, Wqkv, bq, bk, bv, Q, H, 3 * H, 1.0f, 0, 0, 0);

    // Scores: per batch (grid.z), Sc = Q·Kᵀ / 32, fp16
    gemm_bt<2, 8, 32><<<dim3(S / 256, S / 128, B), blk, 0, stream>>>(
        Q, Kp, nullptr, nullptr, nullptr, Sc, H, S, 0.03125f,
        (long)S * H, (long)S * H, (long)S * S);

    // Row softmax: 8192 rows of 2048
    softmax_rows<<<dim3(B * S), blk, 0, stream>>>(Sc, P);

    // O = P·Vtᵀ -> out (fp32)
    gemm_bt<3, 4, 64><<<dim3(H / 128, S / 128, B), blk, 0, stream>>>(
        P, Vt, nullptr, nullptr, nullptr, out, S, H, 1.0f,
        (long)S * S, (long)H * S, (long)S * H);
}

// Round 9
// 264.059 us; speedup vs baseline: 1.0291x; 1.0291x over previous
//
#include <hip/hip_runtime.h>
#include <cstdint>
#include <cstddef>

// Attention: B=4, S=2048, H=1024 (single "head", d=1024). fp32 I/O buffers.
// Pipeline: cvt x,W* to bf16 (1 kernel) ; fused QKV GEMM (N=3072 -> Q,K,Vt) ;
//           Sc = Q·Kᵀ/32 (fp16) ; P = softmax(Sc) (bf16) ; out = P·Vtᵀ (fp32).
// R8 post-mortem: BK 64->32 + wave 64x128 regressed QKV 73->90µs (drain
//   re-exposed: prefetch gets only ~300cyc compute cover vs ~700-900cyc
//   latency; __syncthreads drains vmcnt(0) incl. in-flight prefetch).
//   Scores+PV are ~160µs combined in R7/R8 — dbuf's 64KB LDS halved their
//   occupancy and lost the m114 inter-block overlap that single-buf had.
// R9 consolidation: per-dispatch best-known configs —
//   QKV: BK=64 128x128 dbuf (R7, 73µs);
//   scores/PV: BK=64 128x128 single-buf 32KB, lb(256,4) (R6, 56µs each).
// ws layout (102 MB): [0,16M) xb ; [16,22M) Wqkv bf16 (Wq|Wk|Wv) ;
//   [22,38M) Q ; [38,54M) Kp ; [54,70M) Vt ; [70,102M) Sc fp16 ;
//   P overlays [22,54M) (Q|Kp dead after scores GEMM).

typedef __bf16 bf16;
typedef _Float16 f16;
typedef __bf16 bf16x8 __attribute__((ext_vector_type(8)));
typedef __bf16 bf16x4 __attribute__((ext_vector_type(4)));
typedef float f32x4 __attribute__((ext_vector_type(4)));

#define BM 128
#define BN 128
#define BK 64

// Fused fp32->bf16 convert: x (XQ quads) -> xb, then Wq|Wk|Wv (WQ quads each)
// -> contiguous Wqkv. One dispatch.
#define XQ (8388608 / 4)
#define WQ (1048576 / 4)
__global__ __launch_bounds__(256)
void cvt_all(const float* __restrict__ x, const float* __restrict__ Wq,
             const float* __restrict__ Wk, const float* __restrict__ Wv,
             bf16* __restrict__ xb, bf16* __restrict__ Wqkv)
{
    const int i = blockIdx.x * 256 + threadIdx.x;
    const float* src;
    bf16* dst;
    if (i < XQ) {
        src = x + 4 * (size_t)i;
        dst = xb + 4 * (size_t)i;
    } else {
        const int j = i - XQ;                 // 0 .. 3*WQ-1
        const int w = j / WQ;                 // 0..2
        const int off = j - w * WQ;
        const float* ws_ = (w == 0) ? Wq : (w == 1) ? Wk : Wv;
        src = ws_ + 4 * (size_t)off;
        dst = Wqkv + 4 * (size_t)j;
    }
    f32x4 v = *(const f32x4*)src;
    bf16x4 o;
#pragma unroll
    for (int r = 0; r < 4; ++r) o[r] = (bf16)v[r];
    *(bf16x4*)dst = o;
}

// Stage one 128x64 bf16 tile (16 KB) global -> LDS via global_load_lds w=16.
// Lane at linear chunk p stores LDS slot p (DMA: wave-uniform base + lane*16,
// m104) and fetches global chunk (p&7)^(row&7) of row p>>3 (swizzle measured
// conflict-free in R6).
__device__ __forceinline__ void stage_tile(const bf16* __restrict__ g, int ld,
                                           bf16* lds_generic, int tid)
{
    auto lds3 = (__attribute__((address_space(3))) char*)lds_generic;
    const int wave = tid >> 6;
#pragma unroll
    for (int issue = 0; issue < 4; ++issue) {
        const int p   = issue * 256 + tid;
        const int row = p >> 3;
        const int cp  = p & 7;
        const int c   = cp ^ (row & 7);
        const bf16* gp = g + (size_t)row * ld + c * 8;
        const unsigned wave_base = (unsigned)(issue * 4096 + wave * 1024);
        __builtin_amdgcn_global_load_lds(
            (const __attribute__((address_space(1))) void*)gp,
            (__attribute__((address_space(3))) void*)(lds3 + wave_base),
            16, 0, 0);
    }
}

__device__ __forceinline__ bf16x8 read_frag(const bf16* lds, int row, int chunk)
{
    const int cp = chunk ^ (row & 7);
    return *(const bf16x8*)(lds + row * BK + cp * 8);
}

// OUTMODE: 2 = f16 out, scaled by alpha (scores)
//          3 = f32 out (final O -> d_out)
//          4 = fused QKV: col3>>10 selects {Q,K,Vt}; bias0/1/2 = bq/bk/bv.
// DBUF: 1 = double-buffered cross-iter prefetch (lb 256,2 — 64KB LDS);
//       0 = single-buffer stage->drain->compute (lb 256,4 — 32KB LDS).
template <int OUTMODE, int DBUF>
__global__ __launch_bounds__(256, DBUF ? 2 : 4)
void gemm_bt(const bf16* __restrict__ A, const bf16* __restrict__ Bm,
             const float* __restrict__ bias0, const float* __restrict__ bias1,
             const float* __restrict__ bias2, void* __restrict__ C,
             int K, int N, float alpha, long zA, long zB, long zC)
{
    __shared__ alignas(16) bf16 As[DBUF + 1][BM * BK];
    __shared__ alignas(16) bf16 Bs[DBUF + 1][BN * BK];

    const int tid  = threadIdx.x;
    const int lane = tid & 63;
    const int wid  = tid >> 6;
    const int wr   = (wid >> 1) * 64;   // wave row offset in tile
    const int wc   = (wid & 1) * 64;    // wave col offset in tile
    const int quad = lane >> 4;
    const int l16  = lane & 15;

    const int m0 = blockIdx.y * BM;
    const int n0 = blockIdx.x * BN;
    const int z  = blockIdx.z;

    const bf16* Ab = A + (size_t)z * zA + (size_t)m0 * K;
    const bf16* Bb = Bm + (size_t)z * zB + (size_t)n0 * K;

    f32x4 acc[4][4] = {};

    if (DBUF) {
        stage_tile(Ab, K, As[0], tid);
        stage_tile(Bb, K, Bs[0], tid);
    }

    const int niter = K / BK;
    for (int it = 0; it < niter; ++it) {
        int cur;
        if (DBUF) {
            cur = it & 1;
            __syncthreads();   // buf[cur] staged; prior compute reads done
            if (it + 1 < niter) {
                stage_tile(Ab + (it + 1) * BK, K, As[cur ^ 1], tid);
                stage_tile(Bb + (it + 1) * BK, K, Bs[cur ^ 1], tid);
            }
        } else {
            cur = 0;
            __syncthreads();   // prior iteration's LDS reads complete
            stage_tile(Ab + it * BK, K, As[0], tid);
            stage_tile(Bb + it * BK, K, Bs[0], tid);
            __syncthreads();   // drains vmcnt(0): tiles visible
        }
#pragma unroll
        for (int h = 0; h < 2; ++h) {
            bf16x8 af[4], bfr[4];
#pragma unroll
            for (int i = 0; i < 4; ++i)
                af[i]  = read_frag(As[cur], wr + i * 16 + l16, h * 4 + quad);
#pragma unroll
            for (int j = 0; j < 4; ++j)
                bfr[j] = read_frag(Bs[cur], wc + j * 16 + l16, h * 4 + quad);

#pragma unroll
            for (int i = 0; i < 4; ++i)
#pragma unroll
                for (int j = 0; j < 4; ++j)
                    acc[i][j] = __builtin_amdgcn_mfma_f32_16x16x32_bf16(
                        af[i], bfr[j], acc[i][j], 0, 0, 0);
        }
    }

    // Epilogue. C/D layout (verified m89): col = lane&15, row = quad*4 + reg.
#pragma unroll
    for (int j = 0; j < 4; ++j) {
        const int col3 = n0 + wc + j * 16 + l16;
#pragma unroll
        for (int i = 0; i < 4; ++i) {
            const int rbase = m0 + wr + i * 16 + quad * 4;
            if (OUTMODE == 2) {
                f16* Cf = (f16*)C + (size_t)z * zC;
#pragma unroll
                for (int r = 0; r < 4; ++r)
                    Cf[(size_t)(rbase + r) * N + col3] = (f16)(acc[i][j][r] * alpha);
            } else if (OUTMODE == 3) {
                float* Cf = (float*)C + (size_t)z * zC;
#pragma unroll
                for (int r = 0; r < 4; ++r)
                    Cf[(size_t)(rbase + r) * N + col3] = acc[i][j][r];
            } else { // OUTMODE == 4
                const int mat = col3 >> 10;           // 0=Q 1=K 2=V (uniform/blk)
                const int col = col3 & 1023;
                const float* bp = (mat == 0) ? bias0 : (mat == 1) ? bias1 : bias2;
                const float bj = bp[col];
                if (mat < 2) {
                    bf16* Cb = (bf16*)C + (size_t)mat * (8u << 20);
#pragma unroll
                    for (int r = 0; r < 4; ++r)
                        Cb[(size_t)(rbase + r) * 1024 + col] =
                            (bf16)(acc[i][j][r] + bj);
                } else {
                    // Vt[b][col][s] = V[b*2048+s][col]; quad rows are 4
                    // consecutive s -> one 8B same-type vector store.
                    bf16* Cb = (bf16*)C + (size_t)(16u << 20);
                    const int b = rbase >> 11;
                    const int s = rbase & 2047;
                    bf16x4 tmp;
#pragma unroll
                    for (int r = 0; r < 4; ++r) tmp[r] = (bf16)(acc[i][j][r] + bj);
                    *(bf16x4*)(Cb + (((size_t)((b << 10) + col)) << 11) + s) = tmp;
                }
            }
        }
    }
}

__device__ __forceinline__ float wred_max(float v)
{
#pragma unroll
    for (int o = 32; o > 0; o >>= 1) v = fmaxf(v, __shfl_xor(v, o, 64));
    return v;
}
__device__ __forceinline__ float wred_sum(float v)
{
#pragma unroll
    for (int o = 32; o > 0; o >>= 1) v += __shfl_xor(v, o, 64);
    return v;
}

__global__ __launch_bounds__(256)
void softmax_rows(const f16* __restrict__ Sc, bf16* __restrict__ P)
{
    constexpr int NC = 2048;
    const size_t row = blockIdx.x;
    const f16* src = Sc + row * NC;
    bf16* dst = P + row * NC;
    const int tid = threadIdx.x;

    float v[8];
    float m = -3.4e38f;
#pragma unroll
    for (int i = 0; i < 8; ++i) {
        v[i] = (float)src[tid + 256 * i];
        m = fmaxf(m, v[i]);
    }
    m = wred_max(m);

    __shared__ float redm[4], reds[4];
    if ((tid & 63) == 0) redm[tid >> 6] = m;
    __syncthreads();
    m = fmaxf(fmaxf(redm[0], redm[1]), fmaxf(redm[2], redm[3]));

    float s = 0.f;
#pragma unroll
    for (int i = 0; i < 8; ++i) { v[i] = __expf(v[i] - m); s += v[i]; }
    s = wred_sum(s);
    if ((tid & 63) == 0) reds[tid >> 6] = s;
    __syncthreads();
    s = reds[0] + reds[1] + reds[2] + reds[3];

    const float inv = 1.f / s;
#pragma unroll
    for (int i = 0; i < 8; ++i) dst[tid + 256 * i] = (bf16)(v[i] * inv);
}

extern "C" void kernel_launch(void* const* d_in, const int* in_sizes, int n_in,
                              void* d_out, int out_size, void* d_ws, size_t ws_size,
                              hipStream_t stream)
{
    constexpr int B = 4, S = 2048, H = 1024;
    const float* x  = (const float*)d_in[0];
    const float* Wq = (const float*)d_in[1];
    const float* bq = (const float*)d_in[2];
    const float* Wk = (const float*)d_in[3];
    const float* bk = (const float*)d_in[4];
    const float* Wv = (const float*)d_in[5];
    const float* bv = (const float*)d_in[6];
    float* out = (float*)d_out;

    char* ws = (char*)d_ws;
    bf16* xb   = (bf16*)ws;                         // 16 MB
    bf16* Wqkv = (bf16*)(ws + (size_t)(16 << 20));  //  6 MB (Wq|Wk|Wv bf16)
    bf16* Q    = (bf16*)(ws + (size_t)(22 << 20));  // 16 MB
    bf16* Kp   = (bf16*)(ws + (size_t)(38 << 20));  // 16 MB (Q + 8M elems)
    bf16* Vt   = (bf16*)(ws + (size_t)(54 << 20));  // 16 MB (Q + 16M elems)
    f16*  Sc   = (f16*) (ws + (size_t)(70 << 20));  // 32 MB (fp16 scores)
    bf16* P    = (bf16*)(ws + (size_t)(22 << 20));  // 32 MB, overlays Q|Kp

    dim3 blk(256, 1, 1);

    // fp32 -> bf16 conversions, one dispatch (x -> xb, Wq|Wk|Wv -> Wqkv)
    cvt_all<<<dim3((XQ + 3 * WQ) / 256), blk, 0, stream>>>(
        x, Wq, Wk, Wv, xb, Wqkv);

    // Fused QKV projection: M = 8192, N = 3072, K = 1024 -> Q, Kp, Vt (dbuf)
    gemm_bt<4, 1><<<dim3(3 * H / BN, (B * S) / BM, 1), blk, 0, stream>>>(
        xb, Wqkv, bq, bk, bv, Q, H, 3 * H, 1.0f, 0, 0, 0);

    // Scores: per batch (grid.z), Sc = Q·Kᵀ / 32, fp16 (single-buf, 4 blk/CU)
    gemm_bt<2, 0><<<dim3(S / BN, S / BM, B), blk, 0, stream>>>(
        Q, Kp, nullptr, nullptr, nullptr, Sc, H, S, 0.03125f,
        (long)S * H, (long)S * H, (long)S * S);

    // Row softmax: 8192 rows of 2048
    softmax_rows<<<dim3(B * S), blk, 0, stream>>>(Sc, P);

    // O = P·Vtᵀ -> out (fp32) (single-buf, 4 blk/CU)
    gemm_bt<3, 0><<<dim3(H / BN, S / BM, B), blk, 0, stream>>>(
        P, Vt, nullptr, nullptr, nullptr, out, S, H, 1.0f,
        (long)S * S, (long)H * S, (long)S * H);
}